// Round 12
// baseline (2778.844 us; speedup 1.0000x reference)
//
#include <hip/hip_runtime.h>
#include <hip/hip_bf16.h>

typedef __bf16  bf16_8 __attribute__((ext_vector_type(8)));
typedef short   s16_8  __attribute__((ext_vector_type(8)));
typedef float   f32_4  __attribute__((ext_vector_type(4)));

#define T_ 512

// Issue 8 global_load_dwordx4 (stride 1024B) from b0 (i=0..3), b0+4096 (i=4..7).
#define LD8(d0,d1,d2,d3,d4,d5,d6,d7, BASE)                                  \
  { unsigned long long _b0 = (BASE), _b1 = (BASE) + 4096ull;                \
    asm volatile(                                                           \
      "global_load_dwordx4 %0, %8, off\n\t"                                 \
      "global_load_dwordx4 %1, %8, off offset:1024\n\t"                     \
      "global_load_dwordx4 %2, %8, off offset:2048\n\t"                     \
      "global_load_dwordx4 %3, %8, off offset:3072\n\t"                     \
      "global_load_dwordx4 %4, %9, off\n\t"                                 \
      "global_load_dwordx4 %5, %9, off offset:1024\n\t"                     \
      "global_load_dwordx4 %6, %9, off offset:2048\n\t"                     \
      "global_load_dwordx4 %7, %9, off offset:3072\n\t"                     \
      : "=&v"(d0),"=&v"(d1),"=&v"(d2),"=&v"(d3),                            \
        "=&v"(d4),"=&v"(d5),"=&v"(d6),"=&v"(d7)                             \
      : "v"(_b0), "v"(_b1)); }

// Coherent variant: sc0 sc1 -> bypass L1/L2, read at LLC (where sc1 publishes
// land). Fenceless coherence for the h broadcast (r11-proven).
#define LD8C(d0,d1,d2,d3,d4,d5,d6,d7, BASE)                                 \
  { unsigned long long _b0 = (BASE), _b1 = (BASE) + 4096ull;                \
    asm volatile(                                                           \
      "global_load_dwordx4 %0, %8, off sc0 sc1\n\t"                         \
      "global_load_dwordx4 %1, %8, off offset:1024 sc0 sc1\n\t"             \
      "global_load_dwordx4 %2, %8, off offset:2048 sc0 sc1\n\t"             \
      "global_load_dwordx4 %3, %8, off offset:3072 sc0 sc1\n\t"             \
      "global_load_dwordx4 %4, %9, off sc0 sc1\n\t"                         \
      "global_load_dwordx4 %5, %9, off offset:1024 sc0 sc1\n\t"             \
      "global_load_dwordx4 %6, %9, off offset:2048 sc0 sc1\n\t"             \
      "global_load_dwordx4 %7, %9, off offset:3072 sc0 sc1\n\t"             \
      : "=&v"(d0),"=&v"(d1),"=&v"(d2),"=&v"(d3),                            \
        "=&v"(d4),"=&v"(d5),"=&v"(d6),"=&v"(d7)                             \
      : "v"(_b0), "v"(_b1)); }

// 2 m-tiles (32 batch rows): bases b, b+32768
#define LD16(AF, BASE)                                                      \
  LD8(AF[0][0],AF[0][1],AF[0][2],AF[0][3],AF[0][4],AF[0][5],AF[0][6],AF[0][7], (BASE));          \
  LD8(AF[1][0],AF[1][1],AF[1][2],AF[1][3],AF[1][4],AF[1][5],AF[1][6],AF[1][7], (BASE)+32768ull);

#define LD16C(AF, BASE)                                                     \
  LD8C(AF[0][0],AF[0][1],AF[0][2],AF[0][3],AF[0][4],AF[0][5],AF[0][6],AF[0][7], (BASE));          \
  LD8C(AF[1][0],AF[1][1],AF[1][2],AF[1][3],AF[1][4],AF[1][5],AF[1][6],AF[1][7], (BASE)+32768ull);

#define VMWAIT_FENCE                                                        \
  asm volatile("s_waitcnt vmcnt(0)" ::: "memory");                          \
  __builtin_amdgcn_sched_barrier(0)

// ---------------- P1: X fp32 [T][B][1024] -> xfrag bf16 [T][4 mt][32 kc][64 lane][8]
__global__ __launch_bounds__(256) void p1_xfrag(const float* __restrict__ X,
                                                bf16_8* __restrict__ xf) {
  size_t n = (size_t)blockIdx.x * 256 + threadIdx.x;   // 4,194,304 total
  int lane = (int)(n & 63);
  int kc   = (int)((n >> 6) & 31);
  int mt   = (int)((n >> 11) & 3);
  int t    = (int)(n >> 13);
  int b  = 16 * mt + (lane & 15);
  int i0 = 32 * kc + (lane >> 4) * 8;
  const float4* ps = (const float4*)(X + ((size_t)t * 64 + b) * 1024 + i0);
  float4 a = ps[0], c = ps[1];
  bf16_8 v;
  v[0]=(__bf16)a.x; v[1]=(__bf16)a.y; v[2]=(__bf16)a.z; v[3]=(__bf16)a.w;
  v[4]=(__bf16)c.x; v[5]=(__bf16)c.y; v[6]=(__bf16)c.z; v[7]=(__bf16)c.w;
  xf[n] = v;
}

// ---------------- P2: Wi,Wh fp32 -> wfrag bf16 [256 colblk][64 kc][64 lane][8]
__global__ __launch_bounds__(256) void p2_wfrag(const float* __restrict__ Wi,
                                                const float* __restrict__ Wh,
                                                bf16_8* __restrict__ wf) {
  size_t n = (size_t)blockIdx.x * 256 + threadIdx.x;   // 1,048,576 total
  int lane = (int)(n & 63);
  int kc   = (int)((n >> 6) & 63);
  int cu   = (int)(n >> 12);
  int n16 = lane & 15;
  int g  = n16 >> 2;
  int jj = n16 & 3;
  int col = 4 * cu + jj;
  int k = 32 * kc + (lane >> 4) * 8;
  const float* src = (k < 1024)
      ? (Wi + ((size_t)g * 1024 + col) * 1024 + k)
      : (Wh + ((size_t)g * 1024 + col) * 1024 + (k - 1024));
  const float4* ps = (const float4*)src;
  float4 a = ps[0], c = ps[1];
  bf16_8 v;
  v[0]=(__bf16)a.x; v[1]=(__bf16)a.y; v[2]=(__bf16)a.z; v[3]=(__bf16)a.w;
  v[4]=(__bf16)c.x; v[5]=(__bf16)c.y; v[6]=(__bf16)c.z; v[7]=(__bf16)c.w;
  wf[n] = v;
}

// ---------------- persistent LSTM, dual half-batch chains: 512 blocks x 256 thr
// Block bid: chain S = bid&1 (batch rows S*32..+32), col-block c = bid>>1
// (hcols c*4..+3). 2 blocks/CU co-resident; while one chain's block stalls in
// publish-ack/flag-wait, the other chain's waves compute (HW wave overlap).
// Per chain: own h double-buffer, own 8 group counters + relay flag (r8/r11
// barrier), fenceless h coherence via sc1 publish + sc0sc1 LLC-direct reads.
__global__ __launch_bounds__(256, 2) void lstm_persist(
    const float* __restrict__ bi, const float* __restrict__ bh,
    const s16_8* __restrict__ xfrag, const s16_8* __restrict__ wfrag,
    s16_8* __restrict__ hfrag, float* __restrict__ out,
    unsigned int* __restrict__ ctr)
{
  __shared__ float gx[2][4][32][17];   // x-partials, dbuf           17,408 B
  __shared__ float gh[4][32][17];      // h-partials                  8,704 B
  __shared__ float hvals[4][32];       //                               512 B

  const int tid  = threadIdx.x;
  const int bid  = blockIdx.x;
  const int S    = bid & 1;
  const int c    = bid >> 1;
  const int wv   = tid >> 6;
  const int lane = tid & 63;
  const unsigned long long lofs = (unsigned long long)(wv * 8 * 1024 + lane * 16);

  // resident W B-frags: wave wv covers x-chunks wv*8..+8 and h-chunks 32+wv*8..+8
  s16_8 wxf[8], whf[8];
#pragma unroll
  for (int i = 0; i < 8; ++i) {
    wxf[i] = wfrag[((size_t)c * 64 + wv * 8 + i) * 64 + lane];
    whf[i] = wfrag[((size_t)c * 64 + 32 + wv * 8 + i) * 64 + lane];
  }
#pragma unroll
  for (int i = 0; i < 8; ++i) {
    asm volatile("" : "+v"(wxf[i]));
    asm volatile("" : "+v"(whf[i]));
  }

  // cell identity (tid<128): eb = batch-in-half, ejj = col-in-block
  const int eb  = tid & 31;
  const int ejj = (tid >> 5) & 3;
  const int j   = c * 4 + ejj;
  float bias4[4] = {0.f, 0.f, 0.f, 0.f};
  if (tid < 128) {
#pragma unroll
    for (int g = 0; g < 4; ++g) bias4[g] = bi[g * 1024 + j] + bh[g * 1024 + j];
  }
  float cst = 0.f, hval = 0.f;

  unsigned int* cbase = ctr + S * 1024;          // per-chain counter region
  unsigned int* grp   = cbase + (c >> 5) * 64;   // 8 groups x 32 arrivals
  unsigned int* flag  = cbase + 512;
  unsigned int* oflag = ctr + (1 - S) * 1024 + 512;

  const unsigned long long xchain = (unsigned long long)(const char*)xfrag
                                    + (unsigned)(S * 65536);
  const unsigned long long hchain = (unsigned long long)(const char*)hfrag
                                    + (unsigned)(S * 131072);

  // ---- prologue: gx[0] from x(0)
  {
    s16_8 ax[2][8];
    LD16(ax, xchain + lofs);
    VMWAIT_FENCE;
    f32_4 x0 = {0.f,0.f,0.f,0.f}, x1 = {0.f,0.f,0.f,0.f};
#pragma unroll
    for (int i = 0; i < 8; ++i) {
      x0 = __builtin_amdgcn_mfma_f32_16x16x32_bf16(ax[0][i], wxf[i], x0, 0, 0, 0);
      x1 = __builtin_amdgcn_mfma_f32_16x16x32_bf16(ax[1][i], wxf[i], x1, 0, 0, 0);
    }
#pragma unroll
    for (int r = 0; r < 4; ++r) {
      gx[0][wv][(lane >> 4) * 4 + r][lane & 15]      = x0[r];
      gx[0][wv][16 + (lane >> 4) * 4 + r][lane & 15] = x1[r];
    }
  }
  __syncthreads();

  for (int t = 0; t < T_; ++t) {
    const bool dox = (t + 1 < T_);
    // ---- phase A: h-GEMM(t) [LLC-direct] + x-GEMM(t+1), one load batch
    {
      s16_8 ah[2][8], ax[2][8];
      LD16C(ah, hchain + (unsigned)((t & 1) * 65536) + lofs);
      if (dox) LD16(ax, xchain + (size_t)(t + 1) * 131072 + lofs);
      VMWAIT_FENCE;
      f32_4 h0 = {0.f,0.f,0.f,0.f}, h1 = {0.f,0.f,0.f,0.f};
#pragma unroll
      for (int i = 0; i < 8; ++i) {
        h0 = __builtin_amdgcn_mfma_f32_16x16x32_bf16(ah[0][i], whf[i], h0, 0, 0, 0);
        h1 = __builtin_amdgcn_mfma_f32_16x16x32_bf16(ah[1][i], whf[i], h1, 0, 0, 0);
      }
#pragma unroll
      for (int r = 0; r < 4; ++r) {
        gh[wv][(lane >> 4) * 4 + r][lane & 15]      = h0[r];
        gh[wv][16 + (lane >> 4) * 4 + r][lane & 15] = h1[r];
      }
      if (dox) {
        f32_4 x0 = {0.f,0.f,0.f,0.f}, x1 = {0.f,0.f,0.f,0.f};
#pragma unroll
        for (int i = 0; i < 8; ++i) {
          x0 = __builtin_amdgcn_mfma_f32_16x16x32_bf16(ax[0][i], wxf[i], x0, 0, 0, 0);
          x1 = __builtin_amdgcn_mfma_f32_16x16x32_bf16(ax[1][i], wxf[i], x1, 0, 0, 0);
        }
#pragma unroll
        for (int r = 0; r < 4; ++r) {
          gx[(t + 1) & 1][wv][(lane >> 4) * 4 + r][lane & 15]      = x0[r];
          gx[(t + 1) & 1][wv][16 + (lane >> 4) * 4 + r][lane & 15] = x1[r];
        }
      }
    }
    __syncthreads();

    // ---- phase B: cell update (threads 0..127)
    if (tid < 128) {
      const int xb = t & 1;
      float g4[4];
#pragma unroll
      for (int g = 0; g < 4; ++g) {
        float s = bias4[g];
        const int row = g * 4 + ejj;
#pragma unroll
        for (int w = 0; w < 4; ++w)
          s += gx[xb][w][eb][row] + gh[w][eb][row];
        g4[g] = s;
      }
      float fg = 1.f / (1.f + __expf(-g4[0]));
      float ig = 1.f / (1.f + __expf(-g4[1]));
      float gg = 1.f - 2.f / (__expf(2.f * g4[2]) + 1.f);   // tanh, inf-safe
      float og = 1.f / (1.f + __expf(-g4[3]));
      cst  = fg * cst + ig * gg;
      hval = og * (1.f - 2.f / (__expf(2.f * cst) + 1.f));
      hvals[ejj][eb] = hval;
    }
    __syncthreads();

    // ---- phase C: out store + publish + per-chain relay barrier
    if (wv == 0 && lane < 32) {
      float h0v = hvals[0][lane], h1v = hvals[1][lane],
            h2v = hvals[2][lane], h3v = hvals[3][lane];
      *(float4*)(out + ((size_t)t * 64 + S * 32 + lane) * 1024 + c * 4)
          = make_float4(h0v, h1v, h2v, h3v);
      if (dox) {
        unsigned long long pk =
            (unsigned long long)__builtin_bit_cast(unsigned short, (__bf16)h0v)
          | ((unsigned long long)__builtin_bit_cast(unsigned short, (__bf16)h1v) << 16)
          | ((unsigned long long)__builtin_bit_cast(unsigned short, (__bf16)h2v) << 32)
          | ((unsigned long long)__builtin_bit_cast(unsigned short, (__bf16)h3v) << 48);
        unsigned long long dst = hchain + (unsigned)(((t + 1) & 1) * 65536)
            + (unsigned)((lane >> 4) * 32768 + (c >> 3) * 1024
                         + ((lane & 15) + 16 * ((c & 7) >> 1)) * 16 + (c & 1) * 8);
        __hip_atomic_store((unsigned long long*)dst, pk,
                           __ATOMIC_RELAXED, __HIP_MEMORY_SCOPE_AGENT);
      }
    }
    if (dox) {
      if (wv == 0) {
        asm volatile("s_waitcnt vmcnt(0)" ::: "memory");   // publishes acked at LLC
        if (lane == 0) atomicAdd(grp, 1u);
      }
      if (wv == 1) {
        const unsigned tgt = 32u * (unsigned)(t + 1);
        if (c == 0) {
          if (lane < 8) {
            unsigned int* cc = cbase + lane * 64;
            while (__hip_atomic_load(cc, __ATOMIC_RELAXED, __HIP_MEMORY_SCOPE_AGENT) < tgt)
              __builtin_amdgcn_s_sleep(1);
          }
          if (lane == 8 && t > 2) {    // skew guard: chains stay within 2 steps
            while (__hip_atomic_load(oflag, __ATOMIC_RELAXED, __HIP_MEMORY_SCOPE_AGENT)
                   < (unsigned)(t - 2))
              __builtin_amdgcn_s_sleep(1);
          }
          if (lane == 0)
            __hip_atomic_store(flag, (unsigned)(t + 1), __ATOMIC_RELAXED,
                               __HIP_MEMORY_SCOPE_AGENT);
        } else if (lane == 0) {
          while (__hip_atomic_load(flag, __ATOMIC_RELAXED, __HIP_MEMORY_SCOPE_AGENT)
                 < (unsigned)(t + 1))
            __builtin_amdgcn_s_sleep(1);
        }
      }
    }
    __syncthreads();
  }

  // ---- h_n, c_n
  if (tid < 128) {
    out[(size_t)T_ * 65536 + (size_t)(S * 32 + eb) * 1024 + j] = hval;
    out[(size_t)T_ * 65536 + 65536 + (size_t)(S * 32 + eb) * 1024 + j] = cst;
  }
}

extern "C" void kernel_launch(void* const* d_in, const int* in_sizes, int n_in,
                              void* d_out, int out_size, void* d_ws, size_t ws_size,
                              hipStream_t stream) {
  (void)in_sizes; (void)n_in;
  const float* X  = (const float*)d_in[0];
  const float* Wi = (const float*)d_in[1];
  const float* Wh = (const float*)d_in[2];
  const float* bi = (const float*)d_in[3];
  const float* bh = (const float*)d_in[4];
  float* out = (float*)d_out;

  char* ws = (char*)d_ws;
  const size_t W_BYTES = (size_t)256 * 64 * 64 * 8 * 2;     // 16,777,216
  const size_t H_BYTES = (size_t)2 * 131072;                //    262,144
  const size_t C_BYTES = 16384;
  const size_t X_BYTES = (size_t)512 * 4 * 32 * 64 * 8 * 2; // 67,108,864

  bf16_8* wfrag = (bf16_8*)ws;
  bf16_8* hfrag = (bf16_8*)(ws + W_BYTES);
  unsigned int* ctr = (unsigned int*)(ws + W_BYTES + H_BYTES);

  bf16_8* xfrag;
  if (ws_size >= W_BYTES + H_BYTES + C_BYTES + X_BYTES) {
    xfrag = (bf16_8*)(ws + W_BYTES + H_BYTES + C_BYTES);
  } else {
    // tail of d_out; clobber front 2t-514 stays behind both chains' consumption
    // (skew capped at 2 by the relay guard); final outputs cover everything.
    size_t out_bytes = (size_t)out_size * 4;
    xfrag = (bf16_8*)((char*)d_out + out_bytes - X_BYTES);
  }

  // zero slot 0 of both chains' h buffers (t=0 reads them) + counters/flags
  hipMemsetAsync((char*)hfrag, 0, 65536, stream);
  hipMemsetAsync((char*)hfrag + 131072, 0, 65536, stream);
  hipMemsetAsync(ctr, 0, C_BYTES, stream);

  hipLaunchKernelGGL(p1_xfrag, dim3(16384), dim3(256), 0, stream, X, xfrag);
  hipLaunchKernelGGL(p2_wfrag, dim3(4096), dim3(256), 0, stream, Wi, Wh, wfrag);
  hipLaunchKernelGGL(lstm_persist, dim3(512), dim3(256), 0, stream,
                     bi, bh, (const s16_8*)xfrag, (const s16_8*)wfrag,
                     (s16_8*)hfrag, out, ctr);
}